// Round 1
// baseline (39.137 us; speedup 1.0000x reference)
//
#include <hip/hip_runtime.h>
#include <hip/hip_bf16.h>
#include <math.h>

#define NB 64
#define NTOK 512
#define NH 768
#define NL 30
#define NCAT 2304

typedef __attribute__((ext_vector_type(8))) short short8;
typedef __attribute__((ext_vector_type(4))) float f32x4;

__device__ inline unsigned short f2bf(float f) {
    union { float f; unsigned int u; } v; v.f = f;
    unsigned int u = v.u;
    return (unsigned short)((u + 0x7fffu + ((u >> 16) & 1u)) >> 16);
}

// ---- Kernel 1: span detection + mean + tanh + bf16 convert -----------------
__global__ __launch_bounds__(512)
void k1_spans(const float* __restrict__ hs,      // [NB,NTOK,NH]
              const float* __restrict__ pooled,  // [NB,NH]
              const int* __restrict__ ent,       // [NB,NTOK]
              unsigned short* __restrict__ Abf,  // [3,NB,NH] bf16
              float* __restrict__ loss_slot)
{
    const int b = blockIdx.x;
    const int tid = threadIdx.x;
    if (b == 0 && tid == 0) loss_slot[0] = 0.0f;

    __shared__ unsigned long long smask[8];
    __shared__ int ss1, ss2, sc1, sc2;
    if (tid == 0) { ss1 = 1 << 30; ss2 = 1 << 30; sc1 = 0; sc2 = 0; }
    __syncthreads();

    const int t = tid;                       // one token per thread
    const int e  = ent[b * NTOK + t];
    const int ep = (t == 0) ? 0 : ent[b * NTOK + t - 1];
    const bool start = (e != 0) && (ep == 0);
    unsigned long long m = __ballot(start);
    const int w = tid >> 6, lane = tid & 63;
    if (lane == 0) smask[w] = m;
    __syncthreads();
    int pre = 0;
    for (int ww = 0; ww < w; ++ww) pre += __popcll(smask[ww]);
    unsigned long long le = (lane == 63) ? ~0ull : ((1ull << (lane + 1)) - 1ull);
    pre += __popcll(smask[w] & le);
    const int span = e ? pre : 0;            // run index: 1 = entity1, 2 = entity2
    if (span == 1)      { atomicMin(&ss1, t); atomicAdd(&sc1, 1); }
    else if (span == 2) { atomicMin(&ss2, t); atomicAdd(&sc2, 1); }
    __syncthreads();
    const int s1 = ss1, c1 = sc1, s2 = ss2, c2 = sc2;
    const float i1 = 1.0f / (float)(c1 > 0 ? c1 : 1);
    const float i2 = 1.0f / (float)(c2 > 0 ? c2 : 1);

    for (int hd = tid; hd < NH; hd += 512) {
        float a1 = 0.f, a2 = 0.f;
        for (int j = 0; j < c1; ++j) a1 += hs[((size_t)b * NTOK + s1 + j) * NH + hd];
        for (int j = 0; j < c2; ++j) a2 += hs[((size_t)b * NTOK + s2 + j) * NH + hd];
        Abf[(0 * NB + b) * NH + hd] = f2bf(pooled[b * NH + hd]);
        Abf[(1 * NB + b) * NH + hd] = f2bf(tanhf(a1 * i1));
        Abf[(2 * NB + b) * NH + hd] = f2bf(tanhf(a2 * i2));
    }
}

// ---- Kernel 2: three [64,768]x[768,768] GEMMs via bf16 MFMA ----------------
// grid = 3 mats * 24 col-tiles(32 wide), block = 128 thr (2 waves)
__global__ __launch_bounds__(128)
void k2_gemm(const unsigned short* __restrict__ Abf,
             const float* __restrict__ Wcls, const float* __restrict__ bcls,
             const float* __restrict__ We1,  const float* __restrict__ be1,
             const float* __restrict__ We2,  const float* __restrict__ be2,
             float* __restrict__ C)          // [64, 2304]
{
    const int bx  = blockIdx.x;
    const int mat = bx / 24;
    const int nt  = bx % 24;
    const int n0  = nt * 32;
    const float* Wg = (mat == 0) ? Wcls : (mat == 1) ? We1 : We2;
    const float* bg = (mat == 0) ? bcls : (mat == 1) ? be1 : be2;
    const unsigned short* Ag = Abf + mat * (NB * NH);

    __shared__ unsigned short Al[64 * 40];   // [row][k] bf16, stride 40 (pad)
    __shared__ unsigned short Wl[32 * 40];   // [n][k] bf16 (transposed), stride 40

    const int tid = threadIdx.x;
    const int w = tid >> 6, lane = tid & 63;
    const int l15 = lane & 15, kg = lane >> 4;

    f32x4 acc[4];
    #pragma unroll
    for (int mt = 0; mt < 4; ++mt)
        #pragma unroll
        for (int j = 0; j < 4; ++j) acc[mt][j] = 0.f;

    for (int k0 = 0; k0 < NH; k0 += 32) {
        // stage A: 64 rows x 32 k (bf16 pairs as u32): 1024 words / 128 thr
        #pragma unroll
        for (int it = 0; it < 8; ++it) {
            int p = tid + it * 128;
            int row = p >> 4, kp = p & 15;
            unsigned int v = *(const unsigned int*)(Ag + row * NH + k0 + kp * 2);
            *(unsigned int*)(&Al[row * 40 + kp * 2]) = v;
        }
        // stage W transposed + f32->bf16: 32 n x 16 kpairs = 512 words
        #pragma unroll
        for (int it = 0; it < 4; ++it) {
            int p = tid + it * 128;
            int kp = p >> 5, n = p & 31;
            float f0 = Wg[(size_t)(k0 + kp * 2)     * NH + n0 + n];
            float f1 = Wg[(size_t)(k0 + kp * 2 + 1) * NH + n0 + n];
            unsigned int v = (unsigned int)f2bf(f0) | ((unsigned int)f2bf(f1) << 16);
            *(unsigned int*)(&Wl[n * 40 + kp * 2]) = v;
        }
        __syncthreads();
        // B fragment: lane needs W[k=kg*8+j][n0 + w*16 + l15] -> Wl row (w*16+l15)
        short8 bf = *(const short8*)(&Wl[(w * 16 + l15) * 40 + kg * 8]);
        #pragma unroll
        for (int mt = 0; mt < 4; ++mt) {
            short8 af = *(const short8*)(&Al[(mt * 16 + l15) * 40 + kg * 8]);
            acc[mt] = __builtin_amdgcn_mfma_f32_16x16x32_bf16(af, bf, acc[mt], 0, 0, 0);
        }
        __syncthreads();
    }

    const int col = n0 + w * 16 + l15;
    const float bias = bg[col];
    #pragma unroll
    for (int mt = 0; mt < 4; ++mt)
        #pragma unroll
        for (int j = 0; j < 4; ++j) {
            int row = mt * 16 + kg * 4 + j;       // D: row=(lane>>4)*4+j, col=lane&15
            C[row * NCAT + mat * NH + col] = acc[mt][j] + bias;
        }
}

// ---- Kernel 3: logits + softmax + log_softmax + NLL ------------------------
__global__ __launch_bounds__(256)
void k3_head(const float* __restrict__ C,     // [64,2304]
             const float* __restrict__ Wcat,  // [2304,30]
             const float* __restrict__ bcat,  // [30]
             const int* __restrict__ labels,
             float* __restrict__ out)         // [64*30 + 1]
{
    const int b = blockIdx.x;
    const int tid = threadIdx.x;
    float acc[NL];
    #pragma unroll
    for (int l = 0; l < NL; ++l) acc[l] = 0.f;
    for (int k = tid; k < NCAT; k += 256) {
        const float c = C[b * NCAT + k];
        const float* wr = Wcat + (size_t)k * NL;
        #pragma unroll
        for (int l = 0; l < NL; ++l) acc[l] += c * wr[l];
    }
    #pragma unroll
    for (int l = 0; l < NL; ++l) {
        float v = acc[l];
        v += __shfl_xor(v, 32); v += __shfl_xor(v, 16); v += __shfl_xor(v, 8);
        v += __shfl_xor(v, 4);  v += __shfl_xor(v, 2);  v += __shfl_xor(v, 1);
        acc[l] = v;
    }
    __shared__ float red[NL];
    if (tid < NL) red[tid] = 0.f;
    __syncthreads();
    if ((tid & 63) == 0) {
        #pragma unroll
        for (int l = 0; l < NL; ++l) atomicAdd(&red[l], acc[l]);
    }
    __syncthreads();
    if (tid == 0) {
        const int lab = labels[b];
        float lg[NL];
        float mx = -1e30f;
        #pragma unroll
        for (int l = 0; l < NL; ++l) { lg[l] = red[l] + bcat[l]; mx = fmaxf(mx, lg[l]); }
        float s = 0.f;
        #pragma unroll
        for (int l = 0; l < NL; ++l) { lg[l] = __expf(lg[l] - mx); s += lg[l]; }
        const float inv = 1.0f / s;
        float mx2 = -1e30f, plab = 0.f;
        #pragma unroll
        for (int l = 0; l < NL; ++l) {
            lg[l] *= inv;                         // probs
            out[b * NL + l] = lg[l];
            mx2 = fmaxf(mx2, lg[l]);
            if (l == lab) plab = lg[l];
        }
        float s2 = 0.f;
        #pragma unroll
        for (int l = 0; l < NL; ++l) s2 += __expf(lg[l] - mx2);
        const float logp = plab - (mx2 + __logf(s2));
        atomicAdd(&out[NB * NL], -logp * (1.0f / (float)NB));
    }
}

extern "C" void kernel_launch(void* const* d_in, const int* in_sizes, int n_in,
                              void* d_out, int out_size, void* d_ws, size_t ws_size,
                              hipStream_t stream)
{
    const float* hs     = (const float*)d_in[0];
    const float* pooled = (const float*)d_in[1];
    const int*   ent    = (const int*)d_in[2];
    const int*   labels = (const int*)d_in[3];
    const float* Wcls   = (const float*)d_in[4];
    const float* bcls   = (const float*)d_in[5];
    const float* We1    = (const float*)d_in[6];
    const float* be1    = (const float*)d_in[7];
    const float* We2    = (const float*)d_in[8];
    const float* be2    = (const float*)d_in[9];
    const float* Wcat   = (const float*)d_in[10];
    const float* bcat   = (const float*)d_in[11];
    float* out = (float*)d_out;

    unsigned short* Abf = (unsigned short*)d_ws;                         // 294912 B
    float* C = (float*)((char*)d_ws + (size_t)3 * NB * NH * sizeof(unsigned short));

    k1_spans<<<NB, 512, 0, stream>>>(hs, pooled, ent, Abf, out + NB * NL);
    k2_gemm<<<72, 128, 0, stream>>>(Abf, Wcls, bcls, We1, be1, We2, be2, C);
    k3_head<<<NB, 256, 0, stream>>>(C, Wcat, bcat, labels, out);
}

// Round 2
// 28.773 us; speedup vs baseline: 1.3602x; 1.3602x over previous
//
#include <hip/hip_runtime.h>
#include <hip/hip_bf16.h>
#include <math.h>

#define NB 64
#define NTOK 512
#define NH 768
#define NL 30
#define NLP 32
#define BK 384
#define AST 392   // LDS row stride in bf16 units (784B: 16B-aligned, padded)

typedef __attribute__((ext_vector_type(8))) short short8;
typedef __attribute__((ext_vector_type(4))) float f32x4;

__device__ inline unsigned short f2bf(float f) {
    union { float f; unsigned int u; } v; v.f = f;
    unsigned int u = v.u;
    return (unsigned short)((u + 0x7fffu + ((u >> 16) & 1u)) >> 16);
}
__device__ inline unsigned int pack2(float a, float b) {
    return (unsigned int)f2bf(a) | ((unsigned int)f2bf(b) << 16);
}

// ---- ka: Wcomb^T[m][l][h] = sum_k Wcat_m[k][l] * W_m[h][k]  (bf16 MFMA) ----
// blocks 0..143: (m, h-tile of 16); blocks 144..146: bias dots + loss zero.
__global__ __launch_bounds__(256)
void ka_combine(const float* __restrict__ Wcls, const float* __restrict__ We1,
                const float* __restrict__ We2,  const float* __restrict__ bcls,
                const float* __restrict__ be1,  const float* __restrict__ be2,
                const float* __restrict__ Wcat,
                float* __restrict__ Wcb, float* __restrict__ bcW,
                float* __restrict__ loss_slot)
{
    const int bx = blockIdx.x, tid = threadIdx.x;
    if (bx >= 144) {                       // ---- bias blocks ----
        const int m = bx - 144;
        const float* bv = (m == 0) ? bcls : (m == 1) ? be1 : be2;
        const float* Wc = Wcat + (size_t)m * NH * NL;
        float acc[NL];
        #pragma unroll
        for (int l = 0; l < NL; ++l) acc[l] = 0.f;
        for (int k = tid; k < NH; k += 256) {
            const float v = bv[k];
            const float* wr = Wc + (size_t)k * NL;
            #pragma unroll
            for (int l = 0; l < NL; ++l) acc[l] += v * wr[l];
        }
        __shared__ float red[NL];
        if (tid < NL) red[tid] = 0.f;
        __syncthreads();
        #pragma unroll
        for (int l = 0; l < NL; ++l) {
            float v = acc[l];
            v += __shfl_xor(v, 32); v += __shfl_xor(v, 16); v += __shfl_xor(v, 8);
            v += __shfl_xor(v, 4);  v += __shfl_xor(v, 2);  v += __shfl_xor(v, 1);
            acc[l] = v;
        }
        if ((tid & 63) == 0) {
            #pragma unroll
            for (int l = 0; l < NL; ++l) atomicAdd(&red[l], acc[l]);
        }
        __syncthreads();
        if (tid < NL) bcW[m * NLP + tid] = red[tid];
        if (m == 0 && tid == 0) loss_slot[0] = 0.f;
        return;
    }
    // ---- main combine blocks ----
    const int m = bx / 48, ht = bx % 48, h0 = ht * 16;
    const float* Wm = (m == 0) ? Wcls : (m == 1) ? We1 : We2;
    const float* Wc = Wcat + (size_t)m * NH * NL;

    __shared__ unsigned short Al[NLP * AST];   // A = Wcat^T  [32 l][384 k] bf16
    __shared__ unsigned short Bl[16 * AST];    // B = W rows  [16 h][384 k] bf16
    __shared__ f32x4 Red[8 * 64];              // cross-wave reduction

    const int w = tid >> 6, lane = tid & 63;
    const int l15 = lane & 15, kg = lane >> 4;
    f32x4 acc0 = {0.f, 0.f, 0.f, 0.f}, acc1 = {0.f, 0.f, 0.f, 0.f};

    for (int it = 0; it < 2; ++it) {
        const int k0 = it * BK;
        // stage A (transpose 30x384 slice of Wcat, zero-pad l=30,31)
        #pragma unroll
        for (int i = 0; i < 24; ++i) {
            int p = tid + i * 256;             // p < 6144 = 192 kpairs * 32 l
            int l = p & 31, kp = p >> 5;
            float g0 = 0.f, g1 = 0.f;
            if (l < NL) {
                g0 = Wc[(size_t)(k0 + 2 * kp)     * NL + l];
                g1 = Wc[(size_t)(k0 + 2 * kp + 1) * NL + l];
            }
            *(unsigned int*)&Al[l * AST + 2 * kp] = pack2(g0, g1);
        }
        // stage B (16 W rows, k-contiguous, f32->bf16)
        #pragma unroll
        for (int i = 0; i < 6; ++i) {
            int q = tid + i * 256;             // q < 1536
            int h = q / 96, kq = (q % 96) * 4;
            f32x4 v = *(const f32x4*)(Wm + (size_t)(h0 + h) * NH + k0 + kq);
            unsigned long long pp = (unsigned long long)pack2(v[0], v[1])
                                  | ((unsigned long long)pack2(v[2], v[3]) << 32);
            *(unsigned long long*)&Bl[h * AST + kq] = pp;
        }
        __syncthreads();
        const int kwb = w * 96 + kg * 8;       // per-wave K-slice of 96
        #pragma unroll
        for (int s = 0; s < 3; ++s) {
            const int kb = kwb + s * 32;
            short8 bf = *(const short8*)&Bl[l15 * AST + kb];
            short8 a0 = *(const short8*)&Al[l15 * AST + kb];
            short8 a1 = *(const short8*)&Al[(16 + l15) * AST + kb];
            acc0 = __builtin_amdgcn_mfma_f32_16x16x32_bf16(a0, bf, acc0, 0, 0, 0);
            acc1 = __builtin_amdgcn_mfma_f32_16x16x32_bf16(a1, bf, acc1, 0, 0, 0);
        }
        __syncthreads();
    }
    Red[(w * 2 + 0) * 64 + lane] = acc0;
    Red[(w * 2 + 1) * 64 + lane] = acc1;
    __syncthreads();
    if (tid < 128) {
        const int lt = tid >> 6, ln = tid & 63;
        f32x4 s = Red[(0 + lt) * 64 + ln] + Red[(2 + lt) * 64 + ln]
                + Red[(4 + lt) * 64 + ln] + Red[(6 + lt) * 64 + ln];
        const int hcol = h0 + (ln & 15);
        #pragma unroll
        for (int j = 0; j < 4; ++j) {
            int l = lt * 16 + (ln >> 4) * 4 + j;   // D: row=(lane>>4)*4+j
            Wcb[(size_t)(m * NLP + l) * NH + hcol] = s[j];
        }
    }
}

// ---- kb: spans + mean + tanh + GEMV vs Wcomb + softmax + loss --------------
__global__ __launch_bounds__(512)
void kb_final(const float* __restrict__ hs, const float* __restrict__ pooled,
              const int* __restrict__ ent, const int* __restrict__ labels,
              const float* __restrict__ Wcb, const float* __restrict__ bcW,
              const float* __restrict__ bcat, float* __restrict__ out)
{
    const int b = blockIdx.x, tid = threadIdx.x;
    __shared__ unsigned long long smask[8];
    __shared__ int ss1, ss2, sc1, sc2;
    __shared__ float xsh[3][NH];
    __shared__ float lgsh[NL];
    if (tid == 0) { ss1 = 1 << 30; ss2 = 1 << 30; sc1 = 0; sc2 = 0; }
    __syncthreads();

    const int e  = ent[b * NTOK + tid];
    const int ep = (tid == 0) ? 0 : ent[b * NTOK + tid - 1];
    const bool start = (e != 0) && (ep == 0);
    unsigned long long mk = __ballot(start);
    const int w = tid >> 6, lane = tid & 63;
    if (lane == 0) smask[w] = mk;
    __syncthreads();
    int pre = 0;
    for (int ww = 0; ww < w; ++ww) pre += __popcll(smask[ww]);
    unsigned long long le = (lane == 63) ? ~0ull : ((1ull << (lane + 1)) - 1ull);
    pre += __popcll(smask[w] & le);
    const int span = e ? pre : 0;
    if (span == 1)      { atomicMin(&ss1, tid); atomicAdd(&sc1, 1); }
    else if (span == 2) { atomicMin(&ss2, tid); atomicAdd(&sc2, 1); }
    __syncthreads();
    const int s1 = ss1, c1 = sc1, s2 = ss2, c2 = sc2;
    const float i1 = 1.0f / (float)(c1 > 0 ? c1 : 1);
    const float i2 = 1.0f / (float)(c2 > 0 ? c2 : 1);

    for (int hd = tid; hd < NH; hd += 512) {
        float a1 = 0.f, a2 = 0.f;
        for (int j = 0; j < c1; ++j) a1 += hs[((size_t)b * NTOK + s1 + j) * NH + hd];
        for (int j = 0; j < c2; ++j) a2 += hs[((size_t)b * NTOK + s2 + j) * NH + hd];
        xsh[0][hd] = pooled[b * NH + hd];
        xsh[1][hd] = tanhf(a1 * i1);
        xsh[2][hd] = tanhf(a2 * i2);
    }
    __syncthreads();

    if (tid < 480) {                       // 16 threads per class l
        const int l = tid >> 4, hsb = (tid & 15) * 48;
        float p = 0.f;
        #pragma unroll
        for (int m = 0; m < 3; ++m) {
            const float* wr = Wcb + (size_t)(m * NLP + l) * NH + hsb;
            const float* xr = &xsh[m][hsb];
            #pragma unroll
            for (int i = 0; i < 12; ++i) {
                f32x4 wv = *(const f32x4*)(wr + i * 4);
                f32x4 xv = *(const f32x4*)(xr + i * 4);
                p += wv[0]*xv[0] + wv[1]*xv[1] + wv[2]*xv[2] + wv[3]*xv[3];
            }
        }
        p += __shfl_xor(p, 8); p += __shfl_xor(p, 4);
        p += __shfl_xor(p, 2); p += __shfl_xor(p, 1);
        if ((tid & 15) == 0) lgsh[l] = p;
    }
    __syncthreads();

    if (tid == 0) {
        const int lab = labels[b];
        float lg[NL], mx = -1e30f;
        #pragma unroll
        for (int l = 0; l < NL; ++l) {
            lg[l] = lgsh[l] + bcW[l] + bcW[NLP + l] + bcW[2 * NLP + l] + bcat[l];
            mx = fmaxf(mx, lg[l]);
        }
        float s = 0.f;
        #pragma unroll
        for (int l = 0; l < NL; ++l) { lg[l] = __expf(lg[l] - mx); s += lg[l]; }
        const float inv = 1.0f / s;
        float mx2 = -1e30f, plab = 0.f;
        #pragma unroll
        for (int l = 0; l < NL; ++l) {
            lg[l] *= inv;                  // probs
            out[b * NL + l] = lg[l];
            mx2 = fmaxf(mx2, lg[l]);
            if (l == lab) plab = lg[l];
        }
        float s2 = 0.f;
        #pragma unroll
        for (int l = 0; l < NL; ++l) s2 += __expf(lg[l] - mx2);
        const float logp = plab - (mx2 + __logf(s2));
        atomicAdd(&out[NB * NL], -logp * (1.0f / (float)NB));
    }
}

extern "C" void kernel_launch(void* const* d_in, const int* in_sizes, int n_in,
                              void* d_out, int out_size, void* d_ws, size_t ws_size,
                              hipStream_t stream)
{
    const float* hs     = (const float*)d_in[0];
    const float* pooled = (const float*)d_in[1];
    const int*   ent    = (const int*)d_in[2];
    const int*   labels = (const int*)d_in[3];
    const float* Wcls   = (const float*)d_in[4];
    const float* bcls   = (const float*)d_in[5];
    const float* We1    = (const float*)d_in[6];
    const float* be1    = (const float*)d_in[7];
    const float* We2    = (const float*)d_in[8];
    const float* be2    = (const float*)d_in[9];
    const float* Wcat   = (const float*)d_in[10];
    const float* bcat   = (const float*)d_in[11];
    float* out = (float*)d_out;

    float* Wcb = (float*)d_ws;                     // [3][32][768] f32 = 294912 B
    float* bcW = Wcb + 3 * NLP * NH;               // [3][32] f32

    ka_combine<<<147, 256, 0, stream>>>(Wcls, We1, We2, bcls, be1, be2, Wcat,
                                        Wcb, bcW, out + NB * NL);
    kb_final<<<64, 512, 0, stream>>>(hs, pooled, ent, labels, Wcb, bcW, bcat, out);
}